// Round 5
// baseline (249.507 us; speedup 1.0000x reference)
//
#include <hip/hip_runtime.h>

// LearnedClassVectors R4 — MEASUREMENT PROBE on top of R3.
// R3 (best, 203.6us bench): register-resident bins, barrier-free, 4KB/channel
// contiguous writes. Kernel device time is hidden below the harness poison
// fills (~120us) in the profile; dur_us spans harness fills + kernel.
// R4 adds a second interleaved 201MB store stream into d_ws (never read,
// ws_size-guarded, deterministic) to measure the marginal cost of 201MB of
// writes and back out the kernel's true BW regime:
//   at-floor (6.5TB/s) -> dur ~235us ; 2.6TB/s-bound -> ~280 ; issue-bound -> ~215.
// d_out path is UNCHANGED from R3 (exact).

#define NTHREADS 256
#define NBLOCKS 1024  // 2 b * 32 gd * 16 p-chunks

typedef float fx4 __attribute__((ext_vector_type(4)));

__global__ __launch_bounds__(NTHREADS) void lcv_kernel(
    const float* __restrict__ x,
    const float* __restrict__ vectors,
    float* __restrict__ out,
    float* __restrict__ ws)   // nullptr if ws too small
{
    __shared__ float s_vec[120];

    const int tid = threadIdx.x;
    const int bid = blockIdx.x;
    const int b   = bid >> 9;         // 2
    const int gd  = (bid >> 4) & 31;  // 32
    const int pc  = bid & 15;         // (pd,ph)
    const int pd  = pc >> 2, ph = pc & 3;

    if (tid < 120) s_vec[tid] = vectors[tid];

    const int row = tid >> 3;   // gh
    const int q   = tid & 7;
    const int d   = (gd << 2) + pd;
    const int h   = (row << 2) + ph;
    const fx4* xr = (const fx4*)(x + ((size_t)b << 21))
                  + (((d << 7) + h) << 5) + (q << 2);
    const fx4 xs0 = xr[0], xs1 = xr[1], xs2 = xr[2], xs3 = xr[3];

    __syncthreads();  // s_vec visible

    int roff[4][4];
    const fx4 xs[4] = {xs0, xs1, xs2, xs3};
    #pragma unroll
    for (int k = 0; k < 4; ++k) {
        #pragma unroll
        for (int j = 0; j < 4; ++j) {
            const float xx = xs[k][j];
            const int bin = (xx >= -1000.f) + (xx >= -75.f) + (xx >= 0.f)
                          + (xx >= 15.f)   + (xx >= 25.f)  + (xx >= 40.f)
                          + (xx >= 50.f)   + (xx >= 200.f) + (xx >= 1000.f);
            roff[j][k] = bin * 12;
        }
    }

    const size_t base = ((size_t)((b * 768 + pc * 48) * 32 + gd) << 8) + tid;
    fx4* out4 = (fx4*)out + base;
    fx4* ws4  = ws ? (fx4*)ws + base : nullptr;
    #pragma unroll
    for (int pw = 0; pw < 4; ++pw) {
        const int r0 = roff[pw][0], r1 = roff[pw][1];
        const int r2 = roff[pw][2], r3 = roff[pw][3];
        #pragma unroll
        for (int v = 0; v < 12; ++v) {
            fx4 r;
            r.x = s_vec[r0 + v];
            r.y = s_vec[r1 + v];
            r.z = s_vec[r2 + v];
            r.w = s_vec[r3 + v];
            const int off = (pw * 12 + v) * 8192;
            out4[off] = r;
            if (ws4) ws4[off] = r;   // probe stream: +201MB writes, never read
        }
    }
}

extern "C" void kernel_launch(void* const* d_in, const int* in_sizes, int n_in,
                              void* d_out, int out_size, void* d_ws, size_t ws_size,
                              hipStream_t stream) {
    const float* x       = (const float*)d_in[0];
    const float* vectors = (const float*)d_in[1];
    float* out           = (float*)d_out;
    // probe stream only if workspace can hold a full output copy (201326592 B)
    float* ws = (ws_size >= (size_t)201326592) ? (float*)d_ws : nullptr;
    lcv_kernel<<<NBLOCKS, NTHREADS, 0, stream>>>(x, vectors, out, ws);
}

// Round 6
// 204.684 us; speedup vs baseline: 1.2190x; 1.2190x over previous
//
#include <hip/hip_runtime.h>

// LearnedClassVectors: bucketize fp32 volume into 10 HU bins, gather (10,12)
// embedding, re-tile into 4x4x4 patches -> out (B=2, 768, 32, 32, 32) fp32.
//
// R5: occupancy test on top of R3 (best, 203.6us). Evidence so far:
//  - write chunk size 128B vs 4KB: neutral (R0 204 vs R3 203.6) -> layout done
//  - nt stores: harmful (+10us, R2) -> dropped
//  - marginal write BW (R4 probe): ~4.4 TB/s vs fill's 6.4 TB/s
// Hypothesis: store concurrency (16 waves/CU, long 48-store tail per thread)
// limits the write path. R5 splits the v-loop across 2 sibling blocks:
// 2048 blocks x 256 thr = 32 waves/CU, 24 stores/thread. Siblings re-load the
// same x float4s (+17MB fetch, LLC-absorbed). d_out values identical (exact).

#define NTHREADS 256
#define NBLOCKS 2048  // b(2) x gd(32) x pc(16) x vhalf(2)

typedef float fx4 __attribute__((ext_vector_type(4)));

__global__ __launch_bounds__(NTHREADS) void lcv_kernel(
    const float* __restrict__ x,
    const float* __restrict__ vectors,
    float* __restrict__ out)
{
    __shared__ float s_vec[120];

    const int tid = threadIdx.x;
    const int bid = blockIdx.x;
    const int vh  = bid & 1;           // v half: v = vh*6 + v', v' in [0,6)
    const int pc  = (bid >> 1) & 15;   // (pd,ph)
    const int gd  = (bid >> 5) & 31;
    const int b   = bid >> 10;
    const int pd  = pc >> 2, ph = pc & 3;

    if (tid < 120) s_vec[tid] = vectors[tid];

    // ---- Load this thread's 16 voxels: (d, h, w = 16q..16q+15) ----
    const int row = tid >> 3;   // gh
    const int q   = tid & 7;
    const int d   = (gd << 2) + pd;
    const int h   = (row << 2) + ph;
    const fx4* xr = (const fx4*)(x + ((size_t)b << 21))
                  + (((d << 7) + h) << 5) + (q << 2);
    const fx4 xs0 = xr[0], xs1 = xr[1], xs2 = xr[2], xs3 = xr[3];

    __syncthreads();  // s_vec visible

    // bins -> table row offsets, in registers. roff[pw][k], gw = 4q+k
    int roff[4][4];
    const fx4 xs[4] = {xs0, xs1, xs2, xs3};
    #pragma unroll
    for (int k = 0; k < 4; ++k) {
        #pragma unroll
        for (int j = 0; j < 4; ++j) {
            const float xx = xs[k][j];
            // searchsorted(side='right') == count(edges <= x)
            const int bin = (xx >= -1000.f) + (xx >= -75.f) + (xx >= 0.f)
                          + (xx >= 15.f)   + (xx >= 25.f)  + (xx >= 40.f)
                          + (xx >= 50.f)   + (xx >= 200.f) + (xx >= 1000.f);
            roff[j][k] = bin * 12;
        }
    }

    // ---- Stream this sibling's 24 channels: o = pc*48 + pw*12 + vh*6 + v' ----
    fx4* out4 = (fx4*)out
              + ((size_t)((b * 768 + pc * 48) * 32 + gd) << 8) + tid;
    const int vbase = vh * 6;
    #pragma unroll
    for (int pw = 0; pw < 4; ++pw) {
        const int r0 = roff[pw][0], r1 = roff[pw][1];
        const int r2 = roff[pw][2], r3 = roff[pw][3];
        #pragma unroll
        for (int vp = 0; vp < 6; ++vp) {
            const int v = vbase + vp;
            fx4 r;
            r.x = s_vec[r0 + v];
            r.y = s_vec[r1 + v];
            r.z = s_vec[r2 + v];
            r.w = s_vec[r3 + v];
            out4[(pw * 12 + v) * 8192] = r;
        }
    }
}

extern "C" void kernel_launch(void* const* d_in, const int* in_sizes, int n_in,
                              void* d_out, int out_size, void* d_ws, size_t ws_size,
                              hipStream_t stream) {
    const float* x       = (const float*)d_in[0];
    const float* vectors = (const float*)d_in[1];
    float* out           = (float*)d_out;
    lcv_kernel<<<NBLOCKS, NTHREADS, 0, stream>>>(x, vectors, out);
}